// Round 5
// baseline (1393.162 us; speedup 1.0000x reference)
//
#include <hip/hip_runtime.h>

typedef unsigned int uint;
typedef unsigned short ushort;
typedef short bf16x8 __attribute__((ext_vector_type(8)));
typedef ushort ushort4v __attribute__((ext_vector_type(4)));
typedef float f32x4 __attribute__((ext_vector_type(4)));

#define HD 1024
#define BT 2048
#define NEXP 6
#define MAXR 4096

typedef __attribute__((address_space(1))) void as1_void;
typedef __attribute__((address_space(3))) void as3_void;
#define ASYNC16(g, l) \
  __builtin_amdgcn_global_load_lds((as1_void*)(const void*)(g), (as3_void*)(void*)(l), 16, 0, 0)

// ---------------- bf16 split helpers ----------------
__device__ static inline ushort f32_to_bf16(float f) {
  uint u = __float_as_uint(f);
  u = (u + 0x7fffu + ((u >> 16) & 1u)) >> 16;
  return (ushort)u;
}
__device__ static inline float bf16_to_f32(ushort h) {
  return __uint_as_float(((uint)h) << 16);
}
__device__ static inline void split2(float f, ushort* hi, ushort* lo) {
  ushort h = f32_to_bf16(f);
  *hi = h;
  *lo = f32_to_bf16(f - bf16_to_f32(h));
}

// ---------------- Threefry-2x32 (matches JAX) ----------------
__host__ __device__ static inline unsigned rotl32(unsigned v, int n) {
  return (v << n) | (v >> (32 - n));
}
__host__ __device__ static inline void tf2x32(unsigned k0, unsigned k1,
                                              unsigned x0, unsigned x1,
                                              unsigned* o0, unsigned* o1) {
  unsigned ks0 = k0, ks1 = k1, ks2 = k0 ^ k1 ^ 0x1BD11BDAu;
  x0 += ks0; x1 += ks1;
  const int ra[4] = {13, 15, 26, 6};
  const int rb[4] = {17, 29, 16, 24};
  #pragma unroll
  for (int r = 0; r < 4; ++r) { x0 += x1; x1 = rotl32(x1, ra[r]); x1 ^= x0; }
  x0 += ks1; x1 += ks2 + 1u;
  #pragma unroll
  for (int r = 0; r < 4; ++r) { x0 += x1; x1 = rotl32(x1, rb[r]); x1 ^= x0; }
  x0 += ks2; x1 += ks0 + 2u;
  #pragma unroll
  for (int r = 0; r < 4; ++r) { x0 += x1; x1 = rotl32(x1, ra[r]); x1 ^= x0; }
  x0 += ks0; x1 += ks1 + 3u;
  #pragma unroll
  for (int r = 0; r < 4; ++r) { x0 += x1; x1 = rotl32(x1, rb[r]); x1 ^= x0; }
  x0 += ks1; x1 += ks2 + 4u;
  #pragma unroll
  for (int r = 0; r < 4; ++r) { x0 += x1; x1 = rotl32(x1, ra[r]); x1 ^= x0; }
  x0 += ks2; x1 += ks0 + 5u;
  *o0 = x0; *o1 = x1;
}

// ---------------- init ----------------
__global__ void init_ws_k(int* cnt, float* loss) {
  int t = threadIdx.x;
  if (t < 32) cnt[t] = 0;
  if (t == 32) loss[0] = 0.0f;
}

// ---------------- weight transpose + split: W(K x N) -> Th,Tl (N x K bf16) ----------------
__global__ __launch_bounds__(256) void transpose_split_k(
    const float* __restrict__ W, ushort* __restrict__ Th, ushort* __restrict__ Tl,
    int K, int N) {
  size_t boff = (size_t)blockIdx.z * K * N;
  W += boff; Th += boff; Tl += boff;
  __shared__ float T[32][33];
  int n0 = blockIdx.x * 32, k0 = blockIdx.y * 32;
  int tid = threadIdx.x;
  int r = tid >> 3, c4 = (tid & 7) * 4;
  float4 v = *(const float4*)&W[(size_t)(k0 + r) * N + n0 + c4];
  T[c4 + 0][r] = v.x; T[c4 + 1][r] = v.y; T[c4 + 2][r] = v.z; T[c4 + 3][r] = v.w;
  __syncthreads();
  ushort4v hh, ll;
  #pragma unroll
  for (int j = 0; j < 4; ++j) {
    float f = T[r][c4 + j];
    ushort h, l; split2(f, &h, &l);
    hh[j] = h; ll[j] = l;
  }
  size_t o = (size_t)(n0 + r) * K + k0 + c4;
  *(ushort4v*)&Th[o] = hh;
  *(ushort4v*)&Tl[o] = ll;
}

// ---------------- elementwise split (for input x) ----------------
__global__ __launch_bounds__(256) void split_plain_k(
    const float* __restrict__ X, ushort* __restrict__ Xh, ushort* __restrict__ Xl) {
  size_t i = ((size_t)blockIdx.x * 256 + threadIdx.x) * 4;
  float4 v = *(const float4*)&X[i];
  ushort4v hh, ll;
  float f[4] = {v.x, v.y, v.z, v.w};
  #pragma unroll
  for (int j = 0; j < 4; ++j) { ushort h, l; split2(f[j], &h, &l); hh[j] = h; ll[j] = l; }
  *(ushort4v*)&Xh[i] = hh;
  *(ushort4v*)&Xl[i] = ll;
}

// ---------------- fused MFMA GEMM, 128x64 tile, BK=32, async staging ----------------
// C(MxN) = A(MxK) @ B^T(NxK), 3-product bf16 split.
// MODE 0: +bias -> C f32, + per-rowblock column sums into psum[by*HD+col] (deterministic)
// MODE 1: +bias -> C f32 + Ch/Cl bf16 split
// MODE 2: expert: gather A rows via list, relu, scatter C rows; blockIdx.z = expert
// MODE 3: +bias -> C f32 only (output projection)
template <int MODE>
__global__ __launch_bounds__(256) void gemm_fused_k(
    const ushort* __restrict__ Ah, const ushort* __restrict__ Al,
    const ushort* __restrict__ Bh, const ushort* __restrict__ Bl,
    const float* __restrict__ bias, float* __restrict__ C,
    ushort* __restrict__ Ch, ushort* __restrict__ Cl,
    float* __restrict__ psum,
    const int* __restrict__ cnt, const int* __restrict__ list,
    int N, int K, int ksteps) {
  int row0 = blockIdx.y * 128, col0 = blockIdx.x * 64;
  int nrows = BT;
  if (MODE == 2) {
    int e = blockIdx.z;
    size_t wo = (size_t)e * N * K;
    Bh += wo; Bl += wo;
    nrows = cnt[e];
    list += e * MAXR;
    if (row0 >= nrows) return;
  }
  __shared__ ushort sAh[128 * 32], sAl[128 * 32];
  __shared__ ushort sBh[64 * 32], sBl[64 * 32];
  __shared__ float colred[2][64];
  int tid = threadIdx.x;
  int lane = tid & 63, w = tid >> 6;
  int wm = (w >> 1) * 64, wn = (w & 1) * 32;
  int fr = lane & 15, cq = lane >> 4;

  // ---- staging source pointers (physical LDS slot p == tid for slab0, 256+tid slab1) ----
  int r0s = tid >> 2;                 // 0..63
  int r1s = r0s + 64;                 // 64..127 (A only)
  int sl = tid & 3;
  int cl0 = sl ^ ((r0s ^ (r0s >> 2)) & 3);
  int cl1 = sl ^ ((r1s ^ (r1s >> 2)) & 3);
  int ga0 = row0 + r0s, ga1 = row0 + r1s;
  if (MODE == 2) {
    ga0 = (ga0 < nrows) ? (list[ga0] & (BT - 1)) : 0;
    ga1 = (ga1 < nrows) ? (list[ga1] & (BT - 1)) : 0;
  }
  const ushort* pah0 = Ah + (size_t)ga0 * K + cl0 * 8;
  const ushort* pah1 = Ah + (size_t)ga1 * K + cl1 * 8;
  const ushort* pal0 = Al + (size_t)ga0 * K + cl0 * 8;
  const ushort* pal1 = Al + (size_t)ga1 * K + cl1 * 8;
  const ushort* pbh  = Bh + (size_t)(col0 + r0s) * K + cl0 * 8;
  const ushort* pbl  = Bl + (size_t)(col0 + r0s) * K + cl0 * 8;
  int lbA0 = w * 512;           // wave-uniform LDS bases (ushort units)
  int lbA1 = 2048 + w * 512;
  int lbB  = w * 512;

  // ---- fragment LDS offsets (match staging swizzle) ----
  int offA[4], offB[2];
  #pragma unroll
  for (int i = 0; i < 4; ++i) {
    int rA = wm + i * 16 + fr;
    offA[i] = rA * 32 + ((cq ^ ((rA ^ (rA >> 2)) & 3)) * 8);
  }
  #pragma unroll
  for (int i = 0; i < 2; ++i) {
    int rB = wn + i * 16 + fr;
    offB[i] = rB * 32 + ((cq ^ ((rB ^ (rB >> 2)) & 3)) * 8);
  }

  f32x4 acc[4][2] = {};

  for (int ks = 0; ks < ksteps; ++ks) {
    int ko = ks * 32;
    __syncthreads();
    ASYNC16(pah0 + ko, sAh + lbA0);
    ASYNC16(pah1 + ko, sAh + lbA1);
    ASYNC16(pal0 + ko, sAl + lbA0);
    ASYNC16(pal1 + ko, sAl + lbA1);
    ASYNC16(pbh + ko, sBh + lbB);
    ASYNC16(pbl + ko, sBl + lbB);
    __syncthreads();
    bf16x8 ah[4], al[4], bh[2], bl[2];
    #pragma unroll
    for (int i = 0; i < 4; ++i) {
      ah[i] = *(const bf16x8*)&sAh[offA[i]];
      al[i] = *(const bf16x8*)&sAl[offA[i]];
    }
    #pragma unroll
    for (int i = 0; i < 2; ++i) {
      bh[i] = *(const bf16x8*)&sBh[offB[i]];
      bl[i] = *(const bf16x8*)&sBl[offB[i]];
    }
    #pragma unroll
    for (int mi = 0; mi < 4; ++mi)
      #pragma unroll
      for (int ni = 0; ni < 2; ++ni) {
        acc[mi][ni] = __builtin_amdgcn_mfma_f32_16x16x32_bf16(ah[mi], bh[ni], acc[mi][ni], 0, 0, 0);
        acc[mi][ni] = __builtin_amdgcn_mfma_f32_16x16x32_bf16(ah[mi], bl[ni], acc[mi][ni], 0, 0, 0);
        acc[mi][ni] = __builtin_amdgcn_mfma_f32_16x16x32_bf16(al[mi], bh[ni], acc[mi][ni], 0, 0, 0);
      }
  }

  // ---- epilogue: C/D layout col = lane&15, row = (lane>>4)*4 + reg ----
  if (MODE == 2) {
    #pragma unroll
    for (int mi = 0; mi < 4; ++mi) {
      int rb = row0 + wm + mi * 16 + cq * 4;
      #pragma unroll
      for (int r = 0; r < 4; ++r) {
        int row = rb + r;
        if (row < nrows) {
          size_t dro = (size_t)list[row] * N;
          #pragma unroll
          for (int ni = 0; ni < 2; ++ni)
            C[dro + col0 + wn + ni * 16 + fr] = fmaxf(acc[mi][ni][r], 0.0f);
        }
      }
    }
  } else {
    float bv[2];
    #pragma unroll
    for (int ni = 0; ni < 2; ++ni) bv[ni] = bias[col0 + wn + ni * 16 + fr];
    float cs[2] = {0.0f, 0.0f};
    #pragma unroll
    for (int mi = 0; mi < 4; ++mi) {
      int rb = row0 + wm + mi * 16 + cq * 4;
      #pragma unroll
      for (int r = 0; r < 4; ++r) {
        size_t ro = (size_t)(rb + r) * N;
        #pragma unroll
        for (int ni = 0; ni < 2; ++ni) {
          int col = col0 + wn + ni * 16 + fr;
          float v = acc[mi][ni][r] + bv[ni];
          C[ro + col] = v;
          if (MODE == 0) cs[ni] += v;
          if (MODE == 1) {
            ushort h, l; split2(v, &h, &l);
            Ch[ro + col] = h;
            Cl[ro + col] = l;
          }
        }
      }
    }
    if (MODE == 0) {
      #pragma unroll
      for (int ni = 0; ni < 2; ++ni) {
        cs[ni] += __shfl_down(cs[ni], 32);
        cs[ni] += __shfl_down(cs[ni], 16);
      }
      if (cq == 0) {
        colred[w >> 1][wn + fr] = cs[0];
        colred[w >> 1][wn + 16 + fr] = cs[1];
      }
      __syncthreads();
      if (tid < 64)
        psum[(size_t)blockIdx.y * HD + col0 + tid] = colred[0][tid] + colred[1][tid];
    }
  }
}

// ---------------- gating ----------------
__global__ __launch_bounds__(64) void gating_k(
    const float* __restrict__ xl, const float* __restrict__ wg,
    int* __restrict__ cnt, int* __restrict__ toklist,
    float* __restrict__ g1o, float* __restrict__ g2o,
    float* __restrict__ loss, unsigned key0, unsigned key1) {
  int b = blockIdx.x;
  int lane = threadIdx.x;
  const float* row = xl + (size_t)b * HD;
  float p[NEXP] = {0, 0, 0, 0, 0, 0};
  for (int d = lane; d < HD; d += 64) {
    float xv = row[d];
    const float* w = wg + (size_t)d * NEXP;
    #pragma unroll
    for (int e = 0; e < NEXP; ++e) p[e] += xv * w[e];
  }
  #pragma unroll
  for (int off = 32; off > 0; off >>= 1)
    #pragma unroll
    for (int e = 0; e < NEXP; ++e) p[e] += __shfl_down(p[e], off);
  if (lane == 0) {
    float mx = p[0];
    #pragma unroll
    for (int e = 1; e < NEXP; ++e) mx = fmaxf(mx, p[e]);
    float ex[NEXP], s = 0.0f;
    #pragma unroll
    for (int e = 0; e < NEXP; ++e) { ex[e] = expf(p[e] - mx); s += ex[e]; }
    float raw[NEXP];
    #pragma unroll
    for (int e = 0; e < NEXP; ++e) raw[e] = ex[e] / s;
    int i1 = 0; float gg1 = raw[0];
    #pragma unroll
    for (int e = 1; e < NEXP; ++e) if (raw[e] > gg1) { gg1 = raw[e]; i1 = e; }
    int i2 = -1; float gg2 = -1.0f;
    #pragma unroll
    for (int e = 0; e < NEXP; ++e) {
      float v = (e == i1) ? 0.0f : raw[e];
      if (v > gg2) { gg2 = v; i2 = e; }
    }
    float den = gg1 + gg2 + 1e-9f;
    float g1n = gg1 / den;
    float g2n = gg2 / den;
    unsigned o0, o1;
    tf2x32(key0, key1, 0u, (unsigned)b, &o0, &o1);
    unsigned bits = o0 ^ o1;
    float prob = __uint_as_float((bits >> 9) | 0x3f800000u) - 1.0f;
    int keep = prob < (g2n / 0.2f);
    int s1 = atomicAdd(&cnt[i1], 1);
    toklist[i1 * MAXR + s1] = b;
    g1o[b] = g1n;
    if (keep) {
      int s2 = atomicAdd(&cnt[i2], 1);
      toklist[i2 * MAXR + s2] = BT + b;
      g2o[b] = g2n;
    } else {
      g2o[b] = 0.0f;
    }
    atomicAdd(loss, gg1);
  }
}

// ---------------- combine + column partial sums (32 slices of 64 rows) ----------------
__global__ __launch_bounds__(256) void combine_sum_k(
    const float* __restrict__ xl, const float* __restrict__ eo,
    const float* __restrict__ g1o, const float* __restrict__ g2o,
    float* __restrict__ y, float* __restrict__ psum) {
  int c = blockIdx.x * 256 + threadIdx.x;
  int r0 = blockIdx.y * 64;
  float s = 0.0f;
  for (int r = r0; r < r0 + 64; ++r) {
    float v = xl[(size_t)r * HD + c];
    float w1g = g1o[r];
    v += w1g * eo[(size_t)r * HD + c];
    float w2g = g2o[r];
    if (w2g != 0.0f) v += w2g * eo[(size_t)(r + BT) * HD + c];
    y[(size_t)r * HD + c] = v;
    s += v;
  }
  psum[blockIdx.y * HD + c] = s;
}

// ---------------- centered variance partials; psum has NP slices, psumsq gets 32 ----------------
template <int NP>
__global__ __launch_bounds__(256) void var_partial_k(
    const float* __restrict__ src, const float* __restrict__ psum,
    float* __restrict__ psumsq) {
  int c = blockIdx.x * 256 + threadIdx.x;
  float s = 0.0f;
  #pragma unroll
  for (int i = 0; i < NP; ++i) s += psum[i * HD + c];
  float mu = s * (1.0f / 2048.0f);
  int r0 = blockIdx.y * 64;
  float ss = 0.0f;
  for (int r = r0; r < r0 + 64; ++r) {
    float d = src[(size_t)r * HD + c] - mu;
    ss += d * d;
  }
  psumsq[blockIdx.y * HD + c] = ss;
}

// ---------------- BN apply + relu -> bf16 hi/lo split ----------------
template <int NP>
__global__ __launch_bounds__(256) void bn_split_k(
    const float* __restrict__ src, const float* __restrict__ psum,
    const float* __restrict__ psumsq, const float* __restrict__ gamma,
    const float* __restrict__ beta, ushort* __restrict__ Hh,
    ushort* __restrict__ Hl) {
  int c = blockIdx.x * 256 + threadIdx.x;
  float s = 0.0f, ss = 0.0f;
  #pragma unroll
  for (int i = 0; i < NP; ++i) s += psum[i * HD + c];
  #pragma unroll
  for (int i = 0; i < 32; ++i) ss += psumsq[i * HD + c];
  float mu = s * (1.0f / 2048.0f);
  float var = ss * (1.0f / 2048.0f);
  float inv = 1.0f / sqrtf(var + 1e-5f);
  float ga = gamma[c], be = beta[c];
  int r0 = blockIdx.y * 64;
  for (int r = r0; r < r0 + 64; ++r) {
    float v = src[(size_t)r * HD + c];
    float o = fmaxf(ga * (v - mu) * inv + be, 0.0f);
    ushort h, l; split2(o, &h, &l);
    Hh[(size_t)r * HD + c] = h;
    Hl[(size_t)r * HD + c] = l;
  }
}

// ---------------- loss finalize ----------------
__global__ void finalize_loss_k(const float* __restrict__ loss, float* __restrict__ out) {
  if (threadIdx.x == 0) out[BT * 256] = loss[0] * (0.01f * 36.0f / 12288.0f);
}

extern "C" void kernel_launch(void* const* d_in, const int* in_sizes, int n_in,
                              void* d_out, int out_size, void* d_ws, size_t ws_size,
                              hipStream_t stream) {
  const float* x     = (const float*)d_in[0];
  const float* in_W  = (const float*)d_in[1];
  const float* in_b  = (const float*)d_in[2];
  const float* in_g  = (const float*)d_in[3];
  const float* in_be = (const float*)d_in[4];
  const float* sp_W  = (const float*)d_in[5];
  const float* sp_b  = (const float*)d_in[6];
  const float* sp_g  = (const float*)d_in[7];
  const float* sp_be = (const float*)d_in[8];
  const float* sp_gate = (const float*)d_in[9];
  const float* sp_w1 = (const float*)d_in[10];
  const float* dn_W  = (const float*)d_in[11];
  const float* dn_b  = (const float*)d_in[12];
  const float* dn_g  = (const float*)d_in[13];
  const float* dn_be = (const float*)d_in[14];
  const float* out_W = (const float*)d_in[15];
  const float* out_b = (const float*)d_in[16];
  float* out = (float*)d_out;

  // ---- workspace layout ----
  char* base = (char*)d_ws;
  size_t off = 0;
  auto alloc = [&](size_t bytes) { void* p = base + off; off = (off + bytes + 255) & ~(size_t)255; return p; };
  float*  xl     = (float*)alloc((size_t)BT * HD * 4);          // 8 MB
  float*  y      = (float*)alloc((size_t)BT * HD * 4);          // 8 MB
  float*  eo     = (float*)alloc((size_t)MAXR * HD * 4);        // 16 MB
  float*  psum   = (float*)alloc(32 * HD * 4);
  float*  psumsq = (float*)alloc(32 * HD * 4);
  float*  g1o    = (float*)alloc(BT * 4);
  float*  g2o    = (float*)alloc(BT * 4);
  float*  loss   = (float*)alloc(256);
  int*    cnt    = (int*)alloc(256);
  int*    toklist= (int*)alloc(NEXP * MAXR * 4);
  ushort* Hh     = (ushort*)alloc((size_t)BT * HD * 2);
  ushort* Hl     = (ushort*)alloc((size_t)BT * HD * 2);
  ushort* XLh    = (ushort*)alloc((size_t)BT * HD * 2);
  ushort* XLl    = (ushort*)alloc((size_t)BT * HD * 2);
  ushort* inWTh  = (ushort*)alloc((size_t)2048 * HD * 2);
  ushort* inWTl  = (ushort*)alloc((size_t)2048 * HD * 2);
  ushort* spWTh  = (ushort*)alloc((size_t)4 * HD * HD * 2);
  ushort* spWTl  = (ushort*)alloc((size_t)4 * HD * HD * 2);
  ushort* dnWTh  = (ushort*)alloc((size_t)4 * HD * HD * 2);
  ushort* dnWTl  = (ushort*)alloc((size_t)4 * HD * HD * 2);
  ushort* outWTh = (ushort*)alloc((size_t)HD * 256 * 2);
  ushort* outWTl = (ushort*)alloc((size_t)HD * 256 * 2);
  // w1 transpose region; input-x split aliases its head (dead after input GEMM;
  // w1 transpose launches after the input GEMM in stream order).
  ushort* w1Th   = (ushort*)alloc((size_t)24 * HD * HD * 2);    // 48 MB
  ushort* w1Tl   = (ushort*)alloc((size_t)24 * HD * HD * 2);    // 48 MB
  ushort* Xh     = w1Th;                                        // 2048x2048 bf16 (8 MB)
  ushort* Xl     = w1Th + (size_t)BT * 2048;                    // next 8 MB

  unsigned lk0[4], lk1[4];
  for (int i = 0; i < 4; ++i) tf2x32(0u, 42u, 0u, (unsigned)i, &lk0[i], &lk1[i]);

  dim3 blk(256);
  init_ws_k<<<1, 64, 0, stream>>>(cnt, loss);

  // ---- weight prep (w1 deferred until after input GEMM) ----
  transpose_split_k<<<dim3(32, 64, 1), blk, 0, stream>>>(in_W, inWTh, inWTl, 2048, HD);
  transpose_split_k<<<dim3(32, 32, 4), blk, 0, stream>>>(sp_W, spWTh, spWTl, HD, HD);
  transpose_split_k<<<dim3(32, 32, 4), blk, 0, stream>>>(dn_W, dnWTh, dnWTl, HD, HD);
  transpose_split_k<<<dim3(8, 32, 1), blk, 0, stream>>>(out_W, outWTh, outWTl, HD, 256);
  split_plain_k<<<(BT * 2048) / 1024, blk, 0, stream>>>(x, Xh, Xl);

  // ---- input layer: fused GEMM (xl + psum), then BN ----
  gemm_fused_k<0><<<dim3(16, 16), blk, 0, stream>>>(Xh, Xl, inWTh, inWTl, in_b, xl,
                                                    nullptr, nullptr, psum,
                                                    nullptr, nullptr, HD, 2048, 64);
  // w1 transpose now (Xh/Xl dead)
  transpose_split_k<<<dim3(32, 32, 24), blk, 0, stream>>>(sp_w1, w1Th, w1Tl, HD, HD);
  var_partial_k<16><<<dim3(4, 32), blk, 0, stream>>>(xl, psum, psumsq);
  bn_split_k<16><<<dim3(4, 32), blk, 0, stream>>>(xl, psum, psumsq, in_g, in_be, Hh, Hl);

  // ---- sparse MoE layers ----
  for (int i = 0; i < 4; ++i) {
    gemm_fused_k<1><<<dim3(16, 16), blk, 0, stream>>>(Hh, Hl, spWTh + (size_t)i * HD * HD,
                                                      spWTl + (size_t)i * HD * HD, sp_b + i * HD,
                                                      xl, XLh, XLl, nullptr,
                                                      nullptr, nullptr, HD, HD, 32);
    gating_k<<<BT, 64, 0, stream>>>(xl, sp_gate + (size_t)i * HD * NEXP,
                                    cnt + i * 8, toklist, g1o, g2o, loss, lk0[i], lk1[i]);
    gemm_fused_k<2><<<dim3(16, 32, NEXP), blk, 0, stream>>>(XLh, XLl,
                                                            w1Th + (size_t)i * NEXP * HD * HD,
                                                            w1Tl + (size_t)i * NEXP * HD * HD,
                                                            nullptr, eo, nullptr, nullptr, nullptr,
                                                            cnt + i * 8, toklist, HD, HD, 32);
    combine_sum_k<<<dim3(4, 32), blk, 0, stream>>>(xl, eo, g1o, g2o, y, psum);
    var_partial_k<32><<<dim3(4, 32), blk, 0, stream>>>(y, psum, psumsq);
    bn_split_k<32><<<dim3(4, 32), blk, 0, stream>>>(y, psum, psumsq, sp_g + i * HD,
                                                    sp_be + i * HD, Hh, Hl);
  }

  // ---- dense layers ----
  for (int i = 0; i < 4; ++i) {
    gemm_fused_k<0><<<dim3(16, 16), blk, 0, stream>>>(Hh, Hl, dnWTh + (size_t)i * HD * HD,
                                                      dnWTl + (size_t)i * HD * HD, dn_b + i * HD,
                                                      xl, nullptr, nullptr, psum,
                                                      nullptr, nullptr, HD, HD, 32);
    var_partial_k<16><<<dim3(4, 32), blk, 0, stream>>>(xl, psum, psumsq);
    bn_split_k<16><<<dim3(4, 32), blk, 0, stream>>>(xl, psum, psumsq, dn_g + i * HD,
                                                    dn_be + i * HD, Hh, Hl);
  }

  // ---- output projection: fused bias ----
  gemm_fused_k<3><<<dim3(4, 16), blk, 0, stream>>>(Hh, Hl, outWTh, outWTl, out_b, out,
                                                   nullptr, nullptr, nullptr,
                                                   nullptr, nullptr, 256, HD, 32);
  finalize_loss_k<<<1, 64, 0, stream>>>(loss, out);
}